// Round 1
// baseline (1793.189 us; speedup 1.0000x reference)
//
#include <hip/hip_runtime.h>

#define B_ 32
#define H_ 56
#define W_ 56
#define N_ 3136
#define C_ 256
#define NH_ 8
#define HD_ 32
#define A_ 49
#define SCALE_ 0.17677669529663687f

typedef unsigned short u16;

__device__ __forceinline__ float b2f(u16 u) {
  union { unsigned int i; float f; } x; x.i = ((unsigned int)u) << 16; return x.f;
}
__device__ __forceinline__ u16 f2b(float f) {
  union { float f; unsigned int i; } x; x.f = f;
  unsigned int u = x.i;
  u += 0x7fffu + ((u >> 16) & 1u);   // RNE
  return (u16)(u >> 16);
}

// ---------------------------------------------------------------------------
// Bias precompute: position_bias [NH][A][N], agent_bias [NH][N][A]
// bilinear 7x7 -> 56x56, half-pixel, edge clamp (== jax renormalized triangle)
// ---------------------------------------------------------------------------
__global__ __launch_bounds__(256)
void bias_kernel(const float* __restrict__ an, const float* __restrict__ na,
                 const float* __restrict__ ah, const float* __restrict__ aw,
                 const float* __restrict__ ha, const float* __restrict__ wa,
                 float* __restrict__ posb, float* __restrict__ agb)
{
  const int hh = blockIdx.x / A_;
  const int ag = blockIdx.x % A_;
  __shared__ float an7[A_], na7[A_], ahv[H_], awv[W_], hav[H_], wav[W_];
  const int tid = threadIdx.x;
  if (tid < A_) {
    an7[tid] = an[(hh*A_ + ag)*A_ + tid];
    na7[tid] = na[(hh*A_ + ag)*A_ + tid];
  }
  if (tid < H_) {
    ahv[tid] = ah[(hh*A_ + ag)*H_ + tid];   // (1,NH,A,56,1)
    awv[tid] = aw[(hh*A_ + ag)*W_ + tid];   // (1,NH,A,1,56)
    hav[tid] = ha[(hh*H_ + tid)*A_ + ag];   // (1,NH,56,1,A)
    wav[tid] = wa[(hh*W_ + tid)*A_ + ag];   // (1,NH,1,56,A)
  }
  __syncthreads();
  for (int t = tid; t < N_; t += 256) {
    const int ty = t / W_, tx = t % W_;
    const float py = (ty + 0.5f)*0.125f - 0.5f;
    const float px = (tx + 0.5f)*0.125f - 0.5f;
    const int iy = (int)floorf(py), ix = (int)floorf(px);
    const float fy = py - (float)iy, fx = px - (float)ix;
    const int iy0 = min(max(iy, 0), 6), iy1 = min(iy + 1, 6);
    const int ix0 = min(max(ix, 0), 6), ix1 = min(ix + 1, 6);
    const float w00 = (1.f-fy)*(1.f-fx), w01 = (1.f-fy)*fx;
    const float w10 = fy*(1.f-fx),       w11 = fy*fx;
    const float ban = w00*an7[iy0*7+ix0] + w01*an7[iy0*7+ix1]
                    + w10*an7[iy1*7+ix0] + w11*an7[iy1*7+ix1];
    const float bna = w00*na7[iy0*7+ix0] + w01*na7[iy0*7+ix1]
                    + w10*na7[iy1*7+ix0] + w11*na7[iy1*7+ix1];
    posb[((size_t)(hh*A_ + ag))*N_ + t] = ban + ahv[ty] + awv[tx];
    agb[((size_t)hh*N_ + t)*A_ + ag]    = bna + hav[ty] + wav[tx];
  }
}

// ---------------------------------------------------------------------------
// QKV GEMM: X[100352,256] @ W[256,768] + b, scatter-epilogue to bf16
// q/k/v each laid out [b][nh][t][hd]
// ---------------------------------------------------------------------------
__global__ __launch_bounds__(256)
void gemm_qkv_kernel(const float* __restrict__ X, const float* __restrict__ W,
                     const float* __restrict__ bias,
                     u16* __restrict__ q, u16* __restrict__ k, u16* __restrict__ v)
{
  constexpr int BM=64, BN=64, BK=16, KD=256, ND=768;
  __shared__ float As[BK][BM+4];   // As[k][m], pad 4 keeps 16B align + kills wr conflicts
  __shared__ float Bs[BK][BN];
  const int tid = threadIdx.x;
  const int m0 = blockIdx.y * BM, n0 = blockIdx.x * BN;
  const int tx = tid & 15, ty = tid >> 4;
  float acc[4][4] = {};
  for (int k0 = 0; k0 < KD; k0 += BK) {
    __syncthreads();
    {
      const int col = tid & 15, row0 = tid >> 4;
      #pragma unroll
      for (int r = 0; r < 4; ++r) {
        const int row = row0 + r*16;
        As[col][row] = X[(size_t)(m0+row)*KD + (k0+col)];
      }
    }
    {
      const int col = tid & 63, row0 = tid >> 6;
      #pragma unroll
      for (int r = 0; r < 4; ++r) {
        const int row = row0 + r*4;
        Bs[row][col] = W[(size_t)(k0+row)*ND + (n0+col)];
      }
    }
    __syncthreads();
    #pragma unroll
    for (int kk = 0; kk < BK; ++kk) {
      const float4 a = *(const float4*)&As[kk][ty*4];
      const float4 b = *(const float4*)&Bs[kk][tx*4];
      acc[0][0] += a.x*b.x; acc[0][1] += a.x*b.y; acc[0][2] += a.x*b.z; acc[0][3] += a.x*b.w;
      acc[1][0] += a.y*b.x; acc[1][1] += a.y*b.y; acc[1][2] += a.y*b.z; acc[1][3] += a.y*b.w;
      acc[2][0] += a.z*b.x; acc[2][1] += a.z*b.y; acc[2][2] += a.z*b.z; acc[2][3] += a.z*b.w;
      acc[3][0] += a.w*b.x; acc[3][1] += a.w*b.y; acc[3][2] += a.w*b.z; acc[3][3] += a.w*b.w;
    }
  }
  #pragma unroll
  for (int i = 0; i < 4; ++i) {
    const int gm = m0 + ty*4 + i;
    const int bb = gm / N_, t = gm % N_;
    #pragma unroll
    for (int j = 0; j < 4; ++j) {
      const int gn = n0 + tx*4 + j;
      const float val = acc[i][j] + bias[gn];
      const int part = gn >> 8, cc = gn & 255, hh = cc >> 5, d = cc & 31;
      u16* dst = (part == 0) ? q : ((part == 1) ? k : v);
      dst[(((size_t)(bb*NH_ + hh))*N_ + t)*HD_ + d] = f2b(val);
    }
  }
}

// ---------------------------------------------------------------------------
// Agent pooling: 8x8 mean of q image -> agent [b][nh][49][32] (f32)
// ---------------------------------------------------------------------------
__global__ __launch_bounds__(64)
void pool_kernel(const u16* __restrict__ q, float* __restrict__ agent)
{
  const int blk = blockIdx.x;
  const int ag = blk % A_;
  const int rem = blk / A_;          // b*8+hh
  const int tid = threadIdx.x;
  const int d = tid & 31, half = tid >> 5;
  const int ay = ag / 7, ax = ag % 7;
  const size_t base = (size_t)rem * N_ * HD_;
  float s = 0.f;
  #pragma unroll
  for (int it = 0; it < 32; ++it) {
    const int yy = half*4 + (it >> 3), xx = it & 7;
    const int t = (ay*8 + yy)*W_ + ax*8 + xx;
    s += b2f(q[base + (size_t)t*HD_ + d]);
  }
  s += __shfl_down(s, 32, 64);
  if (tid < 32) agent[(size_t)rem*A_*HD_ + ag*HD_ + d] = s * (1.f/64.f);
}

// ---------------------------------------------------------------------------
// Stage 1: agent_attn = softmax(agent*scale @ K^T + posb); agent_v = attn @ V
// one block per (b,hh); flash-style online softmax over 49 tiles of 64 keys
// ---------------------------------------------------------------------------
__global__ __launch_bounds__(256)
void stage1_kernel(const u16* __restrict__ kmat, const u16* __restrict__ vmat,
                   const float* __restrict__ agent, const float* __restrict__ posb,
                   float* __restrict__ agentv)
{
  constexpr int TN = 64;                 // 3136 = 49 * 64 exactly
  __shared__ float As[A_][HD_];
  __shared__ float Ks[TN][HD_+1];
  __shared__ float Vs[TN][HD_];
  __shared__ float S[A_][TN+1];
  __shared__ float accs[A_*HD_];
  __shared__ float mrow[A_], lrow[A_], frow[A_];
  const int tid = threadIdx.x;
  const int b = blockIdx.x >> 3, hh = blockIdx.x & 7;
  const size_t kvbase = ((size_t)(b*NH_ + hh))*N_*HD_;
  const size_t agbase = ((size_t)(b*NH_ + hh))*A_*HD_;
  for (int i = tid; i < A_*HD_; i += 256) {
    (&As[0][0])[i] = agent[agbase + i] * SCALE_;
    accs[i] = 0.f;
  }
  if (tid < A_) { mrow[tid] = -1e30f; lrow[tid] = 0.f; }
  const float* pb = posb + (size_t)hh*A_*N_;

  for (int t0 = 0; t0 < N_; t0 += TN) {
    __syncthreads();
    for (int i4 = tid; i4 < TN*(HD_/4); i4 += 256) {
      const int tt = i4 >> 3, d4 = (i4 & 7) * 4;
      const size_t g = kvbase + (size_t)(t0+tt)*HD_ + d4;
      const ushort4 ku = *(const ushort4*)&kmat[g];
      const ushort4 vu = *(const ushort4*)&vmat[g];
      Ks[tt][d4+0]=b2f(ku.x); Ks[tt][d4+1]=b2f(ku.y); Ks[tt][d4+2]=b2f(ku.z); Ks[tt][d4+3]=b2f(ku.w);
      Vs[tt][d4+0]=b2f(vu.x); Vs[tt][d4+1]=b2f(vu.y); Vs[tt][d4+2]=b2f(vu.z); Vs[tt][d4+3]=b2f(vu.w);
    }
    __syncthreads();
    for (int idx = tid; idx < A_*TN; idx += 256) {
      const int ag = idx >> 6, tt = idx & 63;
      float s = 0.f;
      #pragma unroll
      for (int d = 0; d < HD_; ++d) s += As[ag][d] * Ks[tt][d];
      S[ag][tt] = s + pb[(size_t)ag*N_ + t0 + tt];
    }
    __syncthreads();
    if (tid < A_) {
      float rm = -1e30f;
      #pragma unroll 8
      for (int tt = 0; tt < TN; ++tt) rm = fmaxf(rm, S[tid][tt]);
      const float nm = fmaxf(mrow[tid], rm);
      const float f = __expf(mrow[tid] - nm);
      frow[tid] = f; mrow[tid] = nm; lrow[tid] *= f;
    }
    __syncthreads();
    for (int idx = tid; idx < A_*TN; idx += 256) {
      const int ag = idx >> 6, tt = idx & 63;
      S[ag][tt] = __expf(S[ag][tt] - mrow[ag]);
    }
    __syncthreads();
    if (tid < A_) {
      float rs = 0.f;
      #pragma unroll 8
      for (int tt = 0; tt < TN; ++tt) rs += S[tid][tt];
      lrow[tid] += rs;
    }
    for (int idx = tid; idx < A_*HD_; idx += 256) {
      const int ag = idx >> 5, d = idx & 31;
      float s = 0.f;
      #pragma unroll 8
      for (int tt = 0; tt < TN; ++tt) s += S[ag][tt] * Vs[tt][d];
      accs[idx] = accs[idx] * frow[ag] + s;
    }
  }
  __syncthreads();
  for (int idx = tid; idx < A_*HD_; idx += 256)
    agentv[agbase + idx] = accs[idx] / lrow[idx >> 5];
}

// ---------------------------------------------------------------------------
// Stage 2: q_attn = softmax(q*scale @ agent^T + agb); out = q_attn @ agent_v
// one thread per token; writes pre[b][t][c]
// ---------------------------------------------------------------------------
__global__ __launch_bounds__(128)
void stage2_kernel(const u16* __restrict__ qmat, const float* __restrict__ agent,
                   const float* __restrict__ agentv, const float* __restrict__ agb,
                   float* __restrict__ pre)
{
  __shared__ float As[A_][HD_];
  __shared__ float AVs[A_][HD_];
  __shared__ float S2[128*A_];
  const int tid = threadIdx.x;
  const int tile = blockIdx.x;                  // 0..24
  const int b = blockIdx.y >> 3, hh = blockIdx.y & 7;
  const size_t agbase = ((size_t)(b*NH_ + hh))*A_*HD_;
  for (int i = tid; i < A_*HD_; i += 128) {
    (&As[0][0])[i]  = agent[agbase + i] * SCALE_;
    (&AVs[0][0])[i] = agentv[agbase + i];
  }
  const int t0 = tile*128;
  const int ntok = min(128, N_ - t0);
  for (int i = tid; i < ntok*A_; i += 128)
    S2[i] = agb[((size_t)hh*N_ + t0)*A_ + i];   // [tt][ag] flat == global layout
  __syncthreads();
  if (tid < ntok) {
    const int t = t0 + tid;
    float4 qv[8];
    const ushort4* qp = (const ushort4*)&qmat[(((size_t)(b*NH_ + hh))*N_ + t)*HD_];
    #pragma unroll
    for (int i = 0; i < 8; ++i) {
      const ushort4 u = qp[i];
      qv[i] = make_float4(b2f(u.x), b2f(u.y), b2f(u.z), b2f(u.w));
    }
    float* srow = &S2[tid*A_];
    float mx = -1e30f;
    for (int ag = 0; ag < A_; ++ag) {
      const float4* arow = (const float4*)&As[ag][0];
      float s = 0.f;
      #pragma unroll
      for (int i = 0; i < 8; ++i) {
        const float4 a = arow[i];
        s += qv[i].x*a.x + qv[i].y*a.y + qv[i].z*a.z + qv[i].w*a.w;
      }
      s += srow[ag];
      srow[ag] = s;
      mx = fmaxf(mx, s);
    }
    float sum = 0.f;
    float o[HD_];
    #pragma unroll
    for (int d = 0; d < HD_; ++d) o[d] = 0.f;
    for (int ag = 0; ag < A_; ++ag) {
      const float p = __expf(srow[ag] - mx);
      sum += p;
      const float4* vrow = (const float4*)&AVs[ag][0];
      #pragma unroll
      for (int i = 0; i < 8; ++i) {
        const float4 a = vrow[i];
        o[i*4+0] += p*a.x; o[i*4+1] += p*a.y; o[i*4+2] += p*a.z; o[i*4+3] += p*a.w;
      }
    }
    const float inv = 1.f / sum;
    float* op = &pre[((size_t)b*N_ + t)*C_ + hh*HD_];
    #pragma unroll
    for (int i = 0; i < 8; ++i)
      ((float4*)op)[i] = make_float4(o[i*4]*inv, o[i*4+1]*inv, o[i*4+2]*inv, o[i*4+3]*inv);
  }
}

// ---------------------------------------------------------------------------
// Depthwise 3x3 conv on v (SAME), accumulates into pre[b][t][c]
// one block per (b,hh,y)
// ---------------------------------------------------------------------------
__global__ __launch_bounds__(256)
void dwc_kernel(const u16* __restrict__ v, const float* __restrict__ w9,
                const float* __restrict__ db, float* __restrict__ pre)
{
  const int blk = blockIdx.x;
  const int y = blk % H_;
  const int rem = blk / H_;            // b*8+hh
  const int hh = rem & 7, b = rem >> 3;
  const int tid = threadIdx.x;
  __shared__ float Vr[3*W_*HD_];
  const size_t vbase = (size_t)rem * N_ * HD_;
  for (int i = tid; i < 3*W_*HD_; i += 256) {
    const int r = i / (W_*HD_);
    const int rest = i - r*(W_*HD_);
    const int yy = y + r - 1;
    Vr[i] = (yy >= 0 && yy < H_) ? b2f(v[vbase + (size_t)yy*W_*HD_ + rest]) : 0.f;
  }
  __syncthreads();
  const int d = tid & 31, xg = tid >> 5;
  const int c = hh*HD_ + d;
  float wr[9];
  #pragma unroll
  for (int j = 0; j < 9; ++j) wr[j] = w9[c*9 + j];
  const float bias = db[c];
  for (int x = xg; x < W_; x += 8) {
    float s = bias;
    #pragma unroll
    for (int ky = 0; ky < 3; ++ky) {
      #pragma unroll
      for (int kx = 0; kx < 3; ++kx) {
        const int xx = x + kx - 1;
        if (xx >= 0 && xx < W_) s += Vr[(ky*W_ + xx)*HD_ + d] * wr[ky*3 + kx];
      }
    }
    pre[((size_t)b*N_ + y*W_ + x)*C_ + c] += s;
  }
}

// ---------------------------------------------------------------------------
// Proj GEMM: pre[100352,256] @ proj_w[256,256] + b -> d_out (f32)
// ---------------------------------------------------------------------------
__global__ __launch_bounds__(256)
void gemm_proj_kernel(const float* __restrict__ X, const float* __restrict__ W,
                      const float* __restrict__ bias, float* __restrict__ out)
{
  constexpr int BM=64, BN=64, BK=16, KD=256, ND=256;
  __shared__ float As[BK][BM+4];
  __shared__ float Bs[BK][BN];
  const int tid = threadIdx.x;
  const int m0 = blockIdx.y * BM, n0 = blockIdx.x * BN;
  const int tx = tid & 15, ty = tid >> 4;
  float acc[4][4] = {};
  for (int k0 = 0; k0 < KD; k0 += BK) {
    __syncthreads();
    {
      const int col = tid & 15, row0 = tid >> 4;
      #pragma unroll
      for (int r = 0; r < 4; ++r) {
        const int row = row0 + r*16;
        As[col][row] = X[(size_t)(m0+row)*KD + (k0+col)];
      }
    }
    {
      const int col = tid & 63, row0 = tid >> 6;
      #pragma unroll
      for (int r = 0; r < 4; ++r) {
        const int row = row0 + r*4;
        Bs[row][col] = W[(size_t)(k0+row)*ND + (n0+col)];
      }
    }
    __syncthreads();
    #pragma unroll
    for (int kk = 0; kk < BK; ++kk) {
      const float4 a = *(const float4*)&As[kk][ty*4];
      const float4 b = *(const float4*)&Bs[kk][tx*4];
      acc[0][0] += a.x*b.x; acc[0][1] += a.x*b.y; acc[0][2] += a.x*b.z; acc[0][3] += a.x*b.w;
      acc[1][0] += a.y*b.x; acc[1][1] += a.y*b.y; acc[1][2] += a.y*b.z; acc[1][3] += a.y*b.w;
      acc[2][0] += a.z*b.x; acc[2][1] += a.z*b.y; acc[2][2] += a.z*b.z; acc[2][3] += a.z*b.w;
      acc[3][0] += a.w*b.x; acc[3][1] += a.w*b.y; acc[3][2] += a.w*b.z; acc[3][3] += a.w*b.w;
    }
  }
  #pragma unroll
  for (int i = 0; i < 4; ++i) {
    const int gm = m0 + ty*4 + i;
    const int gn0 = n0 + tx*4;
    const float4 o = make_float4(acc[i][0] + bias[gn0+0], acc[i][1] + bias[gn0+1],
                                 acc[i][2] + bias[gn0+2], acc[i][3] + bias[gn0+3]);
    *(float4*)&out[(size_t)gm*ND + gn0] = o;
  }
}

// ---------------------------------------------------------------------------
extern "C" void kernel_launch(void* const* d_in, const int* in_sizes, int n_in,
                              void* d_out, int out_size, void* d_ws, size_t ws_size,
                              hipStream_t stream)
{
  (void)in_sizes; (void)n_in; (void)out_size;
  const float* x     = (const float*)d_in[0];
  const float* qkvw  = (const float*)d_in[1];
  const float* qkvb  = (const float*)d_in[2];
  const float* projw = (const float*)d_in[3];
  const float* projb = (const float*)d_in[4];
  const float* dwcw  = (const float*)d_in[5];
  const float* dwcb  = (const float*)d_in[6];
  const float* an    = (const float*)d_in[7];
  const float* na    = (const float*)d_in[8];
  const float* ah    = (const float*)d_in[9];
  const float* aw    = (const float*)d_in[10];
  const float* ha    = (const float*)d_in[11];
  const float* wa    = (const float*)d_in[12];

  const size_t EL = (size_t)B_*NH_*N_*HD_;     // 25,690,112 elements = B*N*C
  char* ws = (char*)d_ws;
  u16*   qb    = (u16*)(ws);
  u16*   kb    = (u16*)(ws + EL*2);
  u16*   vb    = (u16*)(ws + EL*4);
  float* pre   = (float*)(ws + EL*6);
  float* posb  = (float*)(ws + EL*10);
  float* agb   = (float*)(ws + EL*10 + (size_t)NH_*A_*N_*4);
  float* agent = (float*)(ws + EL*10 + (size_t)NH_*A_*N_*8);
  float* agv   = (float*)(ws + EL*10 + (size_t)NH_*A_*N_*8 + (size_t)B_*NH_*A_*HD_*4);
  const size_t NEED = EL*10 + (size_t)NH_*A_*N_*8 + (size_t)B_*NH_*A_*HD_*8;
  if (ws_size < NEED) return;   // avoid OOB scratch writes; bench will flag mismatch

  bias_kernel<<<dim3(NH_*A_), dim3(256), 0, stream>>>(an, na, ah, aw, ha, wa, posb, agb);
  gemm_qkv_kernel<<<dim3(12, 1568), dim3(256), 0, stream>>>(x, qkvw, qkvb, qb, kb, vb);
  pool_kernel<<<dim3(B_*NH_*A_), dim3(64), 0, stream>>>(qb, agent);
  stage1_kernel<<<dim3(B_*NH_), dim3(256), 0, stream>>>(kb, vb, agent, posb, agv);
  stage2_kernel<<<dim3(25, B_*NH_), dim3(128), 0, stream>>>(qb, agent, agv, agb, pre);
  dwc_kernel<<<dim3(B_*NH_*H_), dim3(256), 0, stream>>>(vb, dwcw, dwcb, pre);
  gemm_proj_kernel<<<dim3(4, 1568), dim3(256), 0, stream>>>(pre, projw, projb, (float*)d_out);
}